// Round 1
// baseline (546.075 us; speedup 1.0000x reference)
//
#include <hip/hip_runtime.h>
#include <cstdint>
#include <cstddef>

typedef __bf16 bf16;
typedef __bf16 bf16x8 __attribute__((ext_vector_type(8)));
typedef float  f32x4 __attribute__((ext_vector_type(4)));

#define MFMA16(a, b, c) __builtin_amdgcn_mfma_f32_16x16x32_bf16((a), (b), (c), 0, 0, 0)

// async global->LDS, 16B per lane. LDS dest must be wave-uniform-base + lane*16,
// which all call sites guarantee (ci = i*256 + tid).
__device__ __forceinline__ void gload16(const void* g, void* l) {
    __builtin_amdgcn_global_load_lds(
        (const __attribute__((address_space(1))) unsigned int*)g,
        (__attribute__((address_space(3))) unsigned int*)l,
        16, 0, 0);
}

// ---------------------------------------------------------------------------
// Weight fp32 -> bf16 convert (w_qkv 1152x384, w_proj 384x384)
// ---------------------------------------------------------------------------
__global__ __launch_bounds__(256) void convert_w(
    const float* __restrict__ wqkv, const float* __restrict__ wproj,
    bf16* __restrict__ wq, bf16* __restrict__ wp)
{
    int t = blockIdx.x * 256 + threadIdx.x;      // grid covers 589824
    if (t < 1152 * 384) wq[t] = (bf16)wqkv[t];
    else                wp[t - 1152 * 384] = (bf16)wproj[t - 1152 * 384];
}

// ---------------------------------------------------------------------------
// RMSNorm over channel dim, x [4][384][4096] fp32 -> xn [16384][384] bf16
// ---------------------------------------------------------------------------
__global__ __launch_bounds__(64) void norm_kernel(
    const float* __restrict__ x, const float* __restrict__ gamma,
    bf16* __restrict__ xn)
{
    __shared__ float sG[384];
    int tid = threadIdx.x;
    for (int i = tid; i < 384; i += 64) sG[i] = gamma[i];
    __syncthreads();
    int t = blockIdx.x * 64 + tid;               // 0..16383 (one pixel)
    int b = t >> 12, p = t & 4095;
    const float* xb = x + (size_t)(b * 384) * 4096 + p;
    float ss = 0.f;
    for (int c = 0; c < 384; ++c) { float v = xb[(size_t)c * 4096]; ss += v * v; }
    float scale = 19.595917942265423f / fmaxf(sqrtf(ss), 1e-12f); // sqrt(384)/max(l2,eps)
    bf16* o = xn + (size_t)t * 384;
    for (int c0 = 0; c0 < 384; c0 += 8) {
        bf16x8 v8;
#pragma unroll
        for (int j = 0; j < 8; ++j)
            v8[j] = (bf16)(xb[(size_t)(c0 + j) * 4096] * scale * sG[c0 + j]);
        *(bf16x8*)(o + c0) = v8;
    }
}

// ---------------------------------------------------------------------------
// Generic BT GEMM: C[m][n] = sum_k A[m][k]*B[n][k], K=384 fixed, tiles 128x128.
// mode 0: C bf16 = acc + bias_n[n],  ldc given        (QKV->qk buffer)
// mode 1: C bf16 = acc + bias_m[m],  ldc given        (V^T buffer)
// mode 2: C fp32 out[(b*384+m)*4096+p] = acc + bias_m[m] + resid[idx], n=b*4096+p
// ---------------------------------------------------------------------------
__global__ __launch_bounds__(256) void gemm_bt(
    const bf16* __restrict__ A, const bf16* __restrict__ B,
    const float* __restrict__ bias_m, const float* __restrict__ bias_n,
    const float* __restrict__ resid, void* __restrict__ Cout,
    int mode, int ldc)
{
    __shared__ bf16 sA[128 * 72];   // 144B rows (128B data + 16B pad): 2-way banks
    __shared__ bf16 sB[128 * 72];
    const int tid = threadIdx.x;
    const int l = tid & 63, w = tid >> 6;
    const int lo = l & 15, hi = l >> 4;
    const int wm = w >> 1, wn = w & 1;
    const int m0 = blockIdx.y * 128, n0 = blockIdx.x * 128;

    f32x4 acc[4][4] = {};

    for (int kt = 0; kt < 6; ++kt) {
        __syncthreads();
        const int k0 = kt * 64;
#pragma unroll
        for (int i = 0; i < 5; ++i) {
            int ci = i * 256 + tid;              // 1152 chunks of 16B per tile
            if (ci < 1152) {
                int row = ci / 9, off = ci % 9;  // off==8 loads harmless slack into pad
                gload16(A + (size_t)(m0 + row) * 384 + k0 + off * 8, (char*)sA + ci * 16);
                gload16(B + (size_t)(n0 + row) * 384 + k0 + off * 8, (char*)sB + ci * 16);
            }
        }
        __syncthreads();
#pragma unroll
        for (int ks = 0; ks < 2; ++ks) {
            bf16x8 af[4], bfr[4];
#pragma unroll
            for (int t = 0; t < 4; ++t)
                af[t] = *(const bf16x8*)(sA + (wm * 64 + t * 16 + lo) * 72 + ks * 32 + hi * 8);
#pragma unroll
            for (int t = 0; t < 4; ++t)
                bfr[t] = *(const bf16x8*)(sB + (wn * 64 + t * 16 + lo) * 72 + ks * 32 + hi * 8);
#pragma unroll
            for (int rt = 0; rt < 4; ++rt)
#pragma unroll
                for (int ct = 0; ct < 4; ++ct)
                    acc[rt][ct] = MFMA16(af[rt], bfr[ct], acc[rt][ct]);
        }
    }

    // epilogue: C/D layout col = lo, row = hi*4 + reg
#pragma unroll
    for (int rt = 0; rt < 4; ++rt) {
#pragma unroll
        for (int ct = 0; ct < 4; ++ct) {
            int mb = m0 + wm * 64 + rt * 16 + hi * 4;
            int n  = n0 + wn * 64 + ct * 16 + lo;
            if (mode == 0) {
                bf16* C = (bf16*)Cout;
                float bn = bias_n[n];
#pragma unroll
                for (int r = 0; r < 4; ++r)
                    C[(size_t)(mb + r) * ldc + n] = (bf16)(acc[rt][ct][r] + bn);
            } else if (mode == 1) {
                bf16* C = (bf16*)Cout;
#pragma unroll
                for (int r = 0; r < 4; ++r)
                    C[(size_t)(mb + r) * ldc + n] = (bf16)(acc[rt][ct][r] + bias_m[mb + r]);
            } else {
                float* O = (float*)Cout;
                int bb = n >> 12, p = n & 4095;
#pragma unroll
                for (int r = 0; r < 4; ++r) {
                    int m = mb + r;
                    size_t idx = ((size_t)(bb * 384 + m)) * 4096 + p;
                    O[idx] = acc[rt][ct][r] + bias_m[m] + resid[idx];
                }
            }
        }
    }
}

// ---------------------------------------------------------------------------
// Flash attention: qk [16384][768] bf16 (cols 0..383 Q, 384..767 K),
// vt [384][16384] bf16 (V transposed), obuf [16384][384] bf16.
// Block = 4 waves, Bq=64 (16 q-rows/wave), Bk=32, online softmax in registers.
// ---------------------------------------------------------------------------
__global__ __launch_bounds__(256) void flash_kernel(
    const bf16* __restrict__ qk, const bf16* __restrict__ vt,
    bf16* __restrict__ obuf)
{
    __shared__ bf16 sK[32 * 392];   // rows 784B (768 data + 16 pad)
    __shared__ bf16 sV[384 * 40];   // rows  80B ( 64 data + 16 pad)
    __shared__ bf16 sP[64 * 40];    // rows  80B ( 64 data + 16 pad)
    const int tid = threadIdx.x;
    const int l = tid & 63, w = tid >> 6;
    const int lo = l & 15, hi = l >> 4;
    const int qt = blockIdx.x, b = blockIdx.y;

    // Q A-fragments in registers: rows qt*64 + w*16 + lo, k = ks*32 + hi*8
    bf16x8 qf[12];
    {
        const bf16* qbase = qk + (size_t)(b * 4096 + qt * 64 + w * 16 + lo) * 768;
#pragma unroll
        for (int ks = 0; ks < 12; ++ks)
            qf[ks] = *(const bf16x8*)(qbase + ks * 32 + hi * 8);
    }

    f32x4 acc[24];
#pragma unroll
    for (int dt = 0; dt < 24; ++dt) acc[dt] = (f32x4){0.f, 0.f, 0.f, 0.f};
    float m[4]    = {-1e30f, -1e30f, -1e30f, -1e30f};   // base-2, pre-scaled domain
    float lsum[4] = {0.f, 0.f, 0.f, 0.f};
    const float SC = 0.07362217057594547f;  // (1/sqrt(384)) * log2(e)

    for (int kt = 0; kt < 128; ++kt) {
        __syncthreads();
        {   // stage K tile [32][384] (pad 16B/row) and V^T tile [384][32] (pad 16B/row)
            const char* kb = (const char*)qk + (size_t)(b * 4096 + kt * 32) * 1536 + 768;
#pragma unroll
            for (int i = 0; i < 7; ++i) {
                int ci = i * 256 + tid;
                if (ci < 1568) {                       // 32 rows * 49 chunks
                    int row = ci / 49, off = ci % 49;  // off==48 -> harmless slack
                    gload16(kb + (size_t)row * 1536 + off * 16, (char*)sK + ci * 16);
                }
            }
            const char* vb = (const char*)vt + (size_t)(b * 4096 + kt * 32) * 2;
#pragma unroll
            for (int i = 0; i < 8; ++i) {
                int ci = i * 256 + tid;
                if (ci < 1920) {                       // 384 rows * 5 chunks
                    int row = ci / 5, off = ci % 5;    // off==4 -> harmless slack
                    gload16(vb + (size_t)row * 32768 + off * 16, (char*)sV + ci * 16);
                }
            }
        }
        __syncthreads();

        // S = Q @ K^T : two 16-col tiles
        f32x4 s0 = {0.f, 0.f, 0.f, 0.f}, s1 = {0.f, 0.f, 0.f, 0.f};
#pragma unroll
        for (int ks = 0; ks < 12; ++ks) {
            bf16x8 b0 = *(const bf16x8*)(sK + (size_t)lo * 392 + ks * 32 + hi * 8);
            bf16x8 b1 = *(const bf16x8*)(sK + (size_t)(16 + lo) * 392 + ks * 32 + hi * 8);
            s0 = MFMA16(qf[ks], b0, s0);
            s1 = MFMA16(qf[ks], b1, s1);
        }

        // online softmax; row = hi*4 + r lives across lanes sharing `hi` (cols = lo)
        float alpha[4];
#pragma unroll
        for (int r = 0; r < 4; ++r) {
            float a0 = s0[r] * SC, a1 = s1[r] * SC;
            s0[r] = a0; s1[r] = a1;
            float t = fmaxf(a0, a1);
            t = fmaxf(t, __shfl_xor(t, 1));
            t = fmaxf(t, __shfl_xor(t, 2));
            t = fmaxf(t, __shfl_xor(t, 4));
            t = fmaxf(t, __shfl_xor(t, 8));
            float mn = fmaxf(m[r], t);
            alpha[r] = exp2f(m[r] - mn);
            m[r] = mn;
        }
#pragma unroll
        for (int r = 0; r < 4; ++r) {
            float p0 = exp2f(s0[r] - m[r]);
            float p1 = exp2f(s1[r] - m[r]);
            bf16 pb0 = (bf16)p0, pb1 = (bf16)p1;
            int prow = w * 16 + hi * 4 + r;
            sP[prow * 40 + lo] = pb0;            // C-layout -> A-layout via LDS
            sP[prow * 40 + 16 + lo] = pb1;
            float rs = (float)pb0 + (float)pb1;  // sum what PV actually sees
            rs += __shfl_xor(rs, 1);
            rs += __shfl_xor(rs, 2);
            rs += __shfl_xor(rs, 4);
            rs += __shfl_xor(rs, 8);
            lsum[r] = lsum[r] * alpha[r] + rs;
        }
#pragma unroll
        for (int dt = 0; dt < 24; ++dt) {
            acc[dt][0] *= alpha[0]; acc[dt][1] *= alpha[1];
            acc[dt][2] *= alpha[2]; acc[dt][3] *= alpha[3];
        }
        // O += P @ V  (A-frag from own wave's sP rows; B-frag from V^T rows)
        bf16x8 af = *(const bf16x8*)(sP + (size_t)(w * 16 + lo) * 40 + hi * 8);
#pragma unroll
        for (int dt = 0; dt < 24; ++dt) {
            bf16x8 bv = *(const bf16x8*)(sV + (size_t)(dt * 16 + lo) * 40 + hi * 8);
            acc[dt] = MFMA16(af, bv, acc[dt]);
        }
    }

    float inv[4];
#pragma unroll
    for (int r = 0; r < 4; ++r) inv[r] = 1.0f / lsum[r];
    const size_t row0 = (size_t)(b * 4096 + qt * 64 + w * 16 + hi * 4);
#pragma unroll
    for (int dt = 0; dt < 24; ++dt) {
        int d = dt * 16 + lo;
#pragma unroll
        for (int r = 0; r < 4; ++r)
            obuf[(row0 + r) * 384 + d] = (bf16)(acc[dt][r] * inv[r]);
    }
}

// ---------------------------------------------------------------------------
extern "C" void kernel_launch(void* const* d_in, const int* in_sizes, int n_in,
                              void* d_out, int out_size, void* d_ws, size_t ws_size,
                              hipStream_t stream) {
    const float* x      = (const float*)d_in[0];
    const float* gamma  = (const float*)d_in[1];
    const float* w_qkv  = (const float*)d_in[2];
    const float* b_qkv  = (const float*)d_in[3];
    const float* w_proj = (const float*)d_in[4];
    const float* b_proj = (const float*)d_in[5];
    float* out = (float*)d_out;

    // workspace carve (≈61.2 MiB + slack); order matters: 16B staging overreads
    // at buffer tails must land inside the next ws buffer.
    char* ws = (char*)d_ws;
    bf16* xn = (bf16*)ws;  ws += (size_t)16384 * 384 * 2;   // normalized x, [tok][c]
    bf16* qkb = (bf16*)ws; ws += (size_t)16384 * 768 * 2;   // Q|K, [tok][768]
    bf16* vtb = (bf16*)ws; ws += (size_t)384 * 16384 * 2;   // V^T, [d][tok]
    bf16* ob = (bf16*)ws;  ws += (size_t)16384 * 384 * 2;   // attn out, [tok][d]
    bf16* wq = (bf16*)ws;  ws += (size_t)1152 * 384 * 2;    // w_qkv bf16
    bf16* wp = (bf16*)ws;  ws += (size_t)384 * 384 * 2;     // w_proj bf16 (+slack after)

    convert_w<<<2304, 256, 0, stream>>>(w_qkv, w_proj, wq, wp);
    norm_kernel<<<256, 64, 0, stream>>>(x, gamma, xn);
    // QK: C[tok][o] = xn @ w_qk^T + b_qkv[o], o in [0,768)
    gemm_bt<<<dim3(6, 128), 256, 0, stream>>>(xn, wq, nullptr, b_qkv, nullptr, qkb, 0, 768);
    // V^T: C[d][tok] = w_v @ xn^T + b_qkv[768+d]
    gemm_bt<<<dim3(128, 3), 256, 0, stream>>>(wq + (size_t)768 * 384, xn,
                                              b_qkv + 768, nullptr, nullptr, vtb, 1, 16384);
    flash_kernel<<<dim3(64, 4), 256, 0, stream>>>(qkb, vtb, ob);
    // proj (transposed output) + bias + residual, fp32 out
    gemm_bt<<<dim3(128, 3), 256, 0, stream>>>(wp, ob, b_proj, nullptr, x, out, 2, 0);
}

// Round 2
// 406.588 us; speedup vs baseline: 1.3431x; 1.3431x over previous
//
#include <hip/hip_runtime.h>
#include <cstdint>
#include <cstddef>

typedef __bf16 bf16;
typedef __bf16 bf16x8 __attribute__((ext_vector_type(8)));
typedef float  f32x4 __attribute__((ext_vector_type(4)));
typedef float  f32x16 __attribute__((ext_vector_type(16)));

#define MFMA16(a, b, c) __builtin_amdgcn_mfma_f32_16x16x32_bf16((a), (b), (c), 0, 0, 0)
#define MFMA32(a, b, c) __builtin_amdgcn_mfma_f32_32x32x16_bf16((a), (b), (c), 0, 0, 0)

// async global->LDS, 16B per lane. LDS dest is wave-uniform base + lane*16,
// which all call sites guarantee (ci = i*256 + tid).
__device__ __forceinline__ void gload16(const void* g, void* l) {
    __builtin_amdgcn_global_load_lds(
        (const __attribute__((address_space(1))) unsigned int*)g,
        (__attribute__((address_space(3))) unsigned int*)l,
        16, 0, 0);
}

// ---------------------------------------------------------------------------
// Weight fp32 -> bf16 convert (w_qkv 1152x384, w_proj 384x384)
// ---------------------------------------------------------------------------
__global__ __launch_bounds__(256) void convert_w(
    const float* __restrict__ wqkv, const float* __restrict__ wproj,
    bf16* __restrict__ wq, bf16* __restrict__ wp)
{
    int t = blockIdx.x * 256 + threadIdx.x;      // grid covers 589824
    if (t < 1152 * 384) wq[t] = (bf16)wqkv[t];
    else                wp[t - 1152 * 384] = (bf16)wproj[t - 1152 * 384];
}

// ---------------------------------------------------------------------------
// RMSNorm over channel dim, x [4][384][4096] fp32 -> xn [16384][384] bf16
// ---------------------------------------------------------------------------
__global__ __launch_bounds__(64) void norm_kernel(
    const float* __restrict__ x, const float* __restrict__ gamma,
    bf16* __restrict__ xn)
{
    __shared__ float sG[384];
    int tid = threadIdx.x;
    for (int i = tid; i < 384; i += 64) sG[i] = gamma[i];
    __syncthreads();
    int t = blockIdx.x * 64 + tid;               // 0..16383 (one pixel)
    int b = t >> 12, p = t & 4095;
    const float* xb = x + (size_t)(b * 384) * 4096 + p;
    float ss = 0.f;
    for (int c = 0; c < 384; ++c) { float v = xb[(size_t)c * 4096]; ss += v * v; }
    float scale = 19.595917942265423f / fmaxf(sqrtf(ss), 1e-12f); // sqrt(384)/max(l2,eps)
    bf16* o = xn + (size_t)t * 384;
    for (int c0 = 0; c0 < 384; c0 += 8) {
        bf16x8 v8;
#pragma unroll
        for (int j = 0; j < 8; ++j)
            v8[j] = (bf16)(xb[(size_t)(c0 + j) * 4096] * scale * sG[c0 + j]);
        *(bf16x8*)(o + c0) = v8;
    }
}

// ---------------------------------------------------------------------------
// Generic BT GEMM: C[m][n] = sum_k A[m][k]*B[n][k], K=384 fixed, tiles 128x128.
// mode 0: C bf16 = acc + bias_n[n],  ldc given        (QKV->qk buffer)
// mode 1: C bf16 = acc + bias_m[m],  ldc given        (V^T buffer)
// mode 2: C fp32 out[(b*384+m)*4096+p] = acc + bias_m[m] + resid[idx], n=b*4096+p
// ---------------------------------------------------------------------------
__global__ __launch_bounds__(256) void gemm_bt(
    const bf16* __restrict__ A, const bf16* __restrict__ B,
    const float* __restrict__ bias_m, const float* __restrict__ bias_n,
    const float* __restrict__ resid, void* __restrict__ Cout,
    int mode, int ldc)
{
    __shared__ bf16 sA[128 * 72];   // 144B rows (128B data + 16B pad)
    __shared__ bf16 sB[128 * 72];
    const int tid = threadIdx.x;
    const int l = tid & 63, w = tid >> 6;
    const int lo = l & 15, hi = l >> 4;
    const int wm = w >> 1, wn = w & 1;
    const int m0 = blockIdx.y * 128, n0 = blockIdx.x * 128;

    f32x4 acc[4][4] = {};

    for (int kt = 0; kt < 6; ++kt) {
        __syncthreads();
        const int k0 = kt * 64;
#pragma unroll
        for (int i = 0; i < 5; ++i) {
            int ci = i * 256 + tid;              // 1152 chunks of 16B per tile
            if (ci < 1152) {
                int row = ci / 9, off = ci % 9;  // off==8 loads harmless slack into pad
                gload16(A + (size_t)(m0 + row) * 384 + k0 + off * 8, (char*)sA + ci * 16);
                gload16(B + (size_t)(n0 + row) * 384 + k0 + off * 8, (char*)sB + ci * 16);
            }
        }
        __syncthreads();
#pragma unroll
        for (int ks = 0; ks < 2; ++ks) {
            bf16x8 af[4], bfr[4];
#pragma unroll
            for (int t = 0; t < 4; ++t)
                af[t] = *(const bf16x8*)(sA + (wm * 64 + t * 16 + lo) * 72 + ks * 32 + hi * 8);
#pragma unroll
            for (int t = 0; t < 4; ++t)
                bfr[t] = *(const bf16x8*)(sB + (wn * 64 + t * 16 + lo) * 72 + ks * 32 + hi * 8);
#pragma unroll
            for (int rt = 0; rt < 4; ++rt)
#pragma unroll
                for (int ct = 0; ct < 4; ++ct)
                    acc[rt][ct] = MFMA16(af[rt], bfr[ct], acc[rt][ct]);
        }
    }

    // epilogue: C/D layout col = lo, row = hi*4 + reg
#pragma unroll
    for (int rt = 0; rt < 4; ++rt) {
#pragma unroll
        for (int ct = 0; ct < 4; ++ct) {
            int mb = m0 + wm * 64 + rt * 16 + hi * 4;
            int n  = n0 + wn * 64 + ct * 16 + lo;
            if (mode == 0) {
                bf16* C = (bf16*)Cout;
                float bn = bias_n[n];
#pragma unroll
                for (int r = 0; r < 4; ++r)
                    C[(size_t)(mb + r) * ldc + n] = (bf16)(acc[rt][ct][r] + bn);
            } else if (mode == 1) {
                bf16* C = (bf16*)Cout;
#pragma unroll
                for (int r = 0; r < 4; ++r)
                    C[(size_t)(mb + r) * ldc + n] = (bf16)(acc[rt][ct][r] + bias_m[mb + r]);
            } else {
                float* O = (float*)Cout;
                int bb = n >> 12, p = n & 4095;
#pragma unroll
                for (int r = 0; r < 4; ++r) {
                    int m = mb + r;
                    size_t idx = ((size_t)(bb * 384 + m)) * 4096 + p;
                    O[idx] = acc[rt][ct][r] + bias_m[m] + resid[idx];
                }
            }
        }
    }
}

// ---------------------------------------------------------------------------
// Flash attention, transposed-S form. qk [16384][768] bf16 (Q|K), vt [384][16384].
// Grid (64 qtiles, b*2+half). Block 256 = 4 waves: (wq = q-half, wd = d-half).
// Each wave: S^T[32kv][32q] = K·(SC·Q)^T with kv in regs, q in lanes ->
// softmax per-lane, P^T converts to PV B-frags via shfl_xor(32) in-register,
// O^T[192d][32q] += V^T·P^T. Barriers only around staging. ksplit=2 for
// 2 blocks/CU; partials (unnormalized O + m,l) merged by merge_kernel.
// ---------------------------------------------------------------------------
__global__ __launch_bounds__(256, 2) void flash_kernel(
    const bf16* __restrict__ qk, const bf16* __restrict__ vt,
    bf16* __restrict__ op0, bf16* __restrict__ op1, float* __restrict__ ml)
{
    __shared__ char smem[55808];
    bf16* sK  = (bf16*)smem;             // [32][392]  (784B rows = 49 chunks)
    bf16* sVT = (bf16*)(smem + 25088);   // [384][40]  (80B rows = 5 chunks)
    const int tid = threadIdx.x;
    const int l = tid & 63, w = tid >> 6;
    const int l31 = l & 31, hi2 = l >> 5;
    const int wq = w >> 1, wd = w & 1;
    const int qt = blockIdx.x, bh = blockIdx.y;
    const int b = bh >> 1, half = bh & 1;
    const int q0 = b * 4096 + qt * 64;           // global token base of q-tile
    const int kvbase = b * 4096 + half * 2048;

    // Q B-frags (pre-scaled by SC): lane holds Q[q0+wq*32+l31][ks*16+hi2*8+j]
    const float SC = 0.07362217057594547f;  // (1/sqrt(384)) * log2(e)
    bf16x8 qf[24];
    {
        const bf16* qrow = qk + (size_t)(q0 + wq * 32 + l31) * 768;
#pragma unroll
        for (int ks = 0; ks < 24; ++ks) {
            bf16x8 t = *(const bf16x8*)(qrow + ks * 16 + hi2 * 8);
#pragma unroll
            for (int j = 0; j < 8; ++j) t[j] = (bf16)((float)t[j] * SC);
            qf[ks] = t;
        }
    }

    f32x16 o[6] = {};
    float m = -1e30f, lsum = 0.f;

    for (int kt = 0; kt < 64; ++kt) {
        __syncthreads();
        const int kv0 = kvbase + kt * 32;
        {   // stage K tile [32][384] and V^T tile [384][32]
            const char* kb = (const char*)qk + (size_t)kv0 * 1536 + 768;
#pragma unroll
            for (int i = 0; i < 7; ++i) {
                int ci = i * 256 + tid;
                if (ci < 1568) {                       // 32 rows * 49 chunks
                    int row = ci / 49, off = ci % 49;  // off==48 -> pad slack
                    gload16(kb + (size_t)row * 1536 + off * 16, (char*)sK + ci * 16);
                }
            }
            const char* vb = (const char*)vt + (size_t)kv0 * 2;
#pragma unroll
            for (int i = 0; i < 8; ++i) {
                int ci = i * 256 + tid;
                if (ci < 1920) {                       // 384 rows * 5 chunks
                    int row = ci / 5, off = ci % 5;    // off==4 -> pad slack
                    gload16(vb + (size_t)row * 32768 + off * 16, (char*)sVT + ci * 16);
                }
            }
        }
        __syncthreads();

        // S^T[kv][q]: A = K rows (kv), B = Q regs
        f32x16 s = {};
#pragma unroll
        for (int ks = 0; ks < 24; ++ks) {
            bf16x8 ak = *(const bf16x8*)(sK + (size_t)l31 * 392 + ks * 16 + hi2 * 8);
            s = MFMA32(ak, qf[ks], s);
        }

        // online softmax: kv lives in regs (+xor32 partner), q = l31 per-lane
        float t = s[0];
#pragma unroll
        for (int r = 1; r < 16; ++r) t = fmaxf(t, s[r]);
        t = fmaxf(t, __shfl_xor(t, 32));
        if (__any(t > m)) {                    // new running max (rare after warmup)
            float mn = fmaxf(m, t);
            float alpha = exp2f(m - mn);
            m = mn;
            lsum *= alpha;
#pragma unroll
            for (int dt = 0; dt < 6; ++dt)
#pragma unroll
                for (int r = 0; r < 16; ++r) o[dt][r] *= alpha;
        }
        float p[16];
        float rs = 0.f;
#pragma unroll
        for (int r = 0; r < 16; ++r) { p[r] = exp2f(s[r] - m); rs += p[r]; }
        rs += __shfl_xor(rs, 32);
        lsum += rs;

        // pack P to bf16 dword pairs; build PV B-frags in-register via xor32.
        // reg r holds kv=(r&3)+8*(r>>2)+4*hi2; frag ks needs kv=ks*16+hi2*8+j.
        unsigned int cpk[8];
#pragma unroll
        for (int i = 0; i < 8; ++i) {
            typedef __bf16 bf16x2 __attribute__((ext_vector_type(2)));
            bf16x2 pr = { (bf16)p[2 * i], (bf16)p[2 * i + 1] };
            cpk[i] = *(unsigned int*)&pr;
        }
        bf16x8 pf[2];
#pragma unroll
        for (int ks = 0; ks < 2; ++ks) {
            int base = ks * 4;
            unsigned int x0 = __shfl_xor((int)cpk[base + 0], 32);
            unsigned int x1 = __shfl_xor((int)cpk[base + 1], 32);
            unsigned int x2 = __shfl_xor((int)cpk[base + 2], 32);
            unsigned int x3 = __shfl_xor((int)cpk[base + 3], 32);
            unsigned int dw[4];
            dw[0] = hi2 ? x2 : cpk[base + 0];
            dw[1] = hi2 ? x3 : cpk[base + 1];
            dw[2] = hi2 ? cpk[base + 2] : x0;
            dw[3] = hi2 ? cpk[base + 3] : x1;
            pf[ks] = *(bf16x8*)dw;
        }

        // O^T[d][q] += V^T · P^T
#pragma unroll
        for (int ks = 0; ks < 2; ++ks)
#pragma unroll
            for (int dt = 0; dt < 6; ++dt) {
                bf16x8 av = *(const bf16x8*)(sVT + (size_t)(wd * 192 + dt * 32 + l31) * 40
                                             + ks * 16 + hi2 * 8);
                o[dt] = MFMA32(av, pf[ks], o[dt]);
            }
    }

    // epilogue: per-wave O^T -> O transpose through LDS (sK region, post-barrier)
    __syncthreads();
    float* tr = (float*)(smem + w * 4608);       // [32 q][36 pitch] fp32
    bf16* dst = half ? op1 : op0;
#pragma unroll
    for (int dt = 0; dt < 6; ++dt) {
#pragma unroll
        for (int r = 0; r < 16; ++r) {
            int d = (r & 3) + 8 * (r >> 2) + 4 * hi2;
            tr[l31 * 36 + d] = o[dt][r];
        }
        int q = l >> 1, dh = (l & 1) * 16;       // compiler orders LDS w->r in-wave
        f32x4 v0 = *(f32x4*)(tr + q * 36 + dh + 0);
        f32x4 v1 = *(f32x4*)(tr + q * 36 + dh + 4);
        f32x4 v2 = *(f32x4*)(tr + q * 36 + dh + 8);
        f32x4 v3 = *(f32x4*)(tr + q * 36 + dh + 12);
        bf16x8 h0, h1;
#pragma unroll
        for (int j = 0; j < 4; ++j) {
            h0[j] = (bf16)v0[j]; h0[4 + j] = (bf16)v1[j];
            h1[j] = (bf16)v2[j]; h1[4 + j] = (bf16)v3[j];
        }
        size_t tok = (size_t)(q0 + wq * 32 + q);
        bf16* drow = dst + tok * 384 + wd * 192 + dt * 32 + dh;
        *(bf16x8*)(drow + 0) = h0;
        *(bf16x8*)(drow + 8) = h1;
        __syncthreads();                          // tr region reused next dt by all waves? no:
                                                  // per-wave region, but keep waves in step
    }
    if (wd == 0 && hi2 == 0) {
        int tok = q0 + wq * 32 + l31;
        ml[(size_t)(half * 16384 + tok) * 2 + 0] = m;
        ml[(size_t)(half * 16384 + tok) * 2 + 1] = lsum;
    }
}

// ---------------------------------------------------------------------------
// Merge the two kv-half partials: out = (a0*O0 + a1*O1) / (a0*l0 + a1*l1).
// One wave per token; p1 aliases ob (in-place safe, element-wise).
// ---------------------------------------------------------------------------
__global__ __launch_bounds__(256) void merge_kernel(
    const bf16* __restrict__ p0, const bf16* __restrict__ p1,
    const float* __restrict__ ml, bf16* __restrict__ ob)
{
    int tok = blockIdx.x * 4 + (threadIdx.x >> 6);
    int l = threadIdx.x & 63;
    float m0 = ml[(size_t)tok * 2 + 0], l0 = ml[(size_t)tok * 2 + 1];
    float m1 = ml[(size_t)(16384 + tok) * 2 + 0], l1 = ml[(size_t)(16384 + tok) * 2 + 1];
    float mM = fmaxf(m0, m1);
    float a0 = exp2f(m0 - mM), a1 = exp2f(m1 - mM);
    float inv = 1.0f / (a0 * l0 + a1 * l1);
    float w0 = a0 * inv, w1 = a1 * inv;
    if (l < 48) {
        size_t off = (size_t)tok * 384 + l * 8;
        bf16x8 v0 = *(const bf16x8*)(p0 + off);
        bf16x8 v1 = *(const bf16x8*)(p1 + off);
        bf16x8 r;
#pragma unroll
        for (int j = 0; j < 8; ++j)
            r[j] = (bf16)((float)v0[j] * w0 + (float)v1[j] * w1);
        *(bf16x8*)(ob + off) = r;
    }
}

// ---------------------------------------------------------------------------
extern "C" void kernel_launch(void* const* d_in, const int* in_sizes, int n_in,
                              void* d_out, int out_size, void* d_ws, size_t ws_size,
                              hipStream_t stream) {
    const float* x      = (const float*)d_in[0];
    const float* gamma  = (const float*)d_in[1];
    const float* w_qkv  = (const float*)d_in[2];
    const float* b_qkv  = (const float*)d_in[3];
    const float* w_proj = (const float*)d_in[4];
    const float* b_proj = (const float*)d_in[5];
    float* out = (float*)d_out;

    // workspace carve (~64.4 MiB); staging 16B overreads at buffer tails land
    // in the next ws buffer. xn is dead after the two gemms -> reused as op0.
    char* ws = (char*)d_ws;
    bf16* xn  = (bf16*)ws; ws += (size_t)16384 * 384 * 2;   // normalized x / flash partial-0
    bf16* qkb = (bf16*)ws; ws += (size_t)16384 * 768 * 2;   // Q|K, [tok][768]
    bf16* vtb = (bf16*)ws; ws += (size_t)384 * 16384 * 2;   // V^T, [d][tok]
    bf16* ob  = (bf16*)ws; ws += (size_t)16384 * 384 * 2;   // flash partial-1 / merged attn out
    bf16* wq  = (bf16*)ws; ws += (size_t)1152 * 384 * 2;    // w_qkv bf16
    bf16* wp  = (bf16*)ws; ws += (size_t)384 * 384 * 2;     // w_proj bf16
    float* mlb = (float*)ws; ws += (size_t)2 * 16384 * 2 * 4; // m,l per (half, tok)

    convert_w<<<2304, 256, 0, stream>>>(w_qkv, w_proj, wq, wp);
    norm_kernel<<<256, 64, 0, stream>>>(x, gamma, xn);
    // QK: C[tok][o] = xn @ w_qk^T + b_qkv[o], o in [0,768)
    gemm_bt<<<dim3(6, 128), 256, 0, stream>>>(xn, wq, nullptr, b_qkv, nullptr, qkb, 0, 768);
    // V^T: C[d][tok] = w_v @ xn^T + b_qkv[768+d]
    gemm_bt<<<dim3(128, 3), 256, 0, stream>>>(wq + (size_t)768 * 384, xn,
                                              b_qkv + 768, nullptr, nullptr, vtb, 1, 16384);
    flash_kernel<<<dim3(64, 8), 256, 0, stream>>>(qkb, vtb, xn, ob, mlb);
    merge_kernel<<<4096, 256, 0, stream>>>(xn, ob, mlb, ob);
    // proj (transposed output) + bias + residual, fp32 out
    gemm_bt<<<dim3(128, 3), 256, 0, stream>>>(wp, ob, b_proj, nullptr, x, out, 2, 0);
}

// Round 3
// 346.647 us; speedup vs baseline: 1.5753x; 1.1729x over previous
//
#include <hip/hip_runtime.h>
#include <cstdint>
#include <cstddef>

typedef __bf16 bf16;
typedef __bf16 bf16x8 __attribute__((ext_vector_type(8)));
typedef float  f32x4 __attribute__((ext_vector_type(4)));
typedef float  f32x16 __attribute__((ext_vector_type(16)));

#define MFMA16(a, b, c) __builtin_amdgcn_mfma_f32_16x16x32_bf16((a), (b), (c), 0, 0, 0)
#define MFMA32F8(a, b, c) __builtin_amdgcn_mfma_f32_32x32x16_fp8_fp8((a), (b), (c), 0, 0, 0)

// float -> fp8 e4m3 (OCP), RNE, single byte
__device__ __forceinline__ uint8_t to_fp8(float v) {
    return (uint8_t)(__builtin_amdgcn_cvt_pk_fp8_f32(v, v, 0, false) & 0xff);
}

// async global->LDS, 16B per lane. LDS dest is wave-uniform base + lane*16,
// which all call sites guarantee (ci = i*256 + tid).
__device__ __forceinline__ void gload16(const void* g, void* l) {
    __builtin_amdgcn_global_load_lds(
        (const __attribute__((address_space(1))) unsigned int*)g,
        (__attribute__((address_space(3))) unsigned int*)l,
        16, 0, 0);
}

// ---------------------------------------------------------------------------
// Weight fp32 -> bf16 convert (w_qkv 1152x384, w_proj 384x384)
// ---------------------------------------------------------------------------
__global__ __launch_bounds__(256) void convert_w(
    const float* __restrict__ wqkv, const float* __restrict__ wproj,
    bf16* __restrict__ wq, bf16* __restrict__ wp)
{
    int t = blockIdx.x * 256 + threadIdx.x;      // grid covers 589824
    if (t < 1152 * 384) wq[t] = (bf16)wqkv[t];
    else                wp[t - 1152 * 384] = (bf16)wproj[t - 1152 * 384];
}

// ---------------------------------------------------------------------------
// RMSNorm over channel dim, x [4][384][4096] fp32 -> xn [16384][384] bf16
// ---------------------------------------------------------------------------
__global__ __launch_bounds__(64) void norm_kernel(
    const float* __restrict__ x, const float* __restrict__ gamma,
    bf16* __restrict__ xn)
{
    __shared__ float sG[384];
    int tid = threadIdx.x;
    for (int i = tid; i < 384; i += 64) sG[i] = gamma[i];
    __syncthreads();
    int t = blockIdx.x * 64 + tid;               // 0..16383 (one pixel)
    int b = t >> 12, p = t & 4095;
    const float* xb = x + (size_t)(b * 384) * 4096 + p;
    float ss = 0.f;
    for (int c = 0; c < 384; ++c) { float v = xb[(size_t)c * 4096]; ss += v * v; }
    float scale = 19.595917942265423f / fmaxf(sqrtf(ss), 1e-12f); // sqrt(384)/max(l2,eps)
    bf16* o = xn + (size_t)t * 384;
    for (int c0 = 0; c0 < 384; c0 += 8) {
        bf16x8 v8;
#pragma unroll
        for (int j = 0; j < 8; ++j)
            v8[j] = (bf16)(xb[(size_t)(c0 + j) * 4096] * scale * sG[c0 + j]);
        *(bf16x8*)(o + c0) = v8;
    }
}

// ---------------------------------------------------------------------------
// Generic BT GEMM: C[m][n] = sum_k A[m][k]*B[n][k], K=384 fixed, tiles 128x128.
// mode 0: C fp8 = acc + bias_n[n],  ldc given        (QK -> qkb buffer)
// mode 1: C fp8 = acc + bias_m[m],  ldc given        (V^T buffer)
// mode 2: C fp32 out[(b*384+m)*4096+p] = acc + bias_m[m] + resid[idx], n=b*4096+p
// ---------------------------------------------------------------------------
__global__ __launch_bounds__(256) void gemm_bt(
    const bf16* __restrict__ A, const bf16* __restrict__ B,
    const float* __restrict__ bias_m, const float* __restrict__ bias_n,
    const float* __restrict__ resid, void* __restrict__ Cout,
    int mode, int ldc)
{
    __shared__ bf16 sA[128 * 72];   // 144B rows (128B data + 16B pad)
    __shared__ bf16 sB[128 * 72];
    const int tid = threadIdx.x;
    const int l = tid & 63, w = tid >> 6;
    const int lo = l & 15, hi = l >> 4;
    const int wm = w >> 1, wn = w & 1;
    const int m0 = blockIdx.y * 128, n0 = blockIdx.x * 128;

    f32x4 acc[4][4] = {};

    for (int kt = 0; kt < 6; ++kt) {
        __syncthreads();
        const int k0 = kt * 64;
#pragma unroll
        for (int i = 0; i < 5; ++i) {
            int ci = i * 256 + tid;              // 1152 chunks of 16B per tile
            if (ci < 1152) {
                int row = ci / 9, off = ci % 9;  // off==8 loads harmless slack into pad
                gload16(A + (size_t)(m0 + row) * 384 + k0 + off * 8, (char*)sA + ci * 16);
                gload16(B + (size_t)(n0 + row) * 384 + k0 + off * 8, (char*)sB + ci * 16);
            }
        }
        __syncthreads();
#pragma unroll
        for (int ks = 0; ks < 2; ++ks) {
            bf16x8 af[4], bfr[4];
#pragma unroll
            for (int t = 0; t < 4; ++t)
                af[t] = *(const bf16x8*)(sA + (wm * 64 + t * 16 + lo) * 72 + ks * 32 + hi * 8);
#pragma unroll
            for (int t = 0; t < 4; ++t)
                bfr[t] = *(const bf16x8*)(sB + (wn * 64 + t * 16 + lo) * 72 + ks * 32 + hi * 8);
#pragma unroll
            for (int rt = 0; rt < 4; ++rt)
#pragma unroll
                for (int ct = 0; ct < 4; ++ct)
                    acc[rt][ct] = MFMA16(af[rt], bfr[ct], acc[rt][ct]);
        }
    }

    // epilogue: C/D layout col = lo, row = hi*4 + reg
#pragma unroll
    for (int rt = 0; rt < 4; ++rt) {
#pragma unroll
        for (int ct = 0; ct < 4; ++ct) {
            int mb = m0 + wm * 64 + rt * 16 + hi * 4;
            int n  = n0 + wn * 64 + ct * 16 + lo;
            if (mode == 0) {
                uint8_t* C = (uint8_t*)Cout;
                float bn = bias_n[n];
#pragma unroll
                for (int r = 0; r < 4; ++r)
                    C[(size_t)(mb + r) * ldc + n] = to_fp8(acc[rt][ct][r] + bn);
            } else if (mode == 1) {
                uint8_t* C = (uint8_t*)Cout;
#pragma unroll
                for (int r = 0; r < 4; ++r)
                    C[(size_t)(mb + r) * ldc + n] = to_fp8(acc[rt][ct][r] + bias_m[mb + r]);
            } else {
                float* O = (float*)Cout;
                int bb = n >> 12, p = n & 4095;
#pragma unroll
                for (int r = 0; r < 4; ++r) {
                    int m = mb + r;
                    size_t idx = ((size_t)(bb * 384 + m)) * 4096 + p;
                    O[idx] = acc[rt][ct][r] + bias_m[m] + resid[idx];
                }
            }
        }
    }
}

// ---------------------------------------------------------------------------
// Flash attention, transposed-S, fp8 operands. qk [16384][768] fp8 (Q|K),
// vt [384][16384] fp8 (V^T). Grid (64 qtiles, b*2+half). Block 256 = 4 waves
// (wq = q-half, wd = d-half). S^T[32kv][32q] = K·Q^T via fp8 MFMA (kv in regs,
// q in lanes), per-lane online softmax in raw-score domain (SC folded into
// exp2), P^T -> fp8 B-frags via 4 shfl_xor(32), O^T[192d][32q] += V^T·P^T.
// Partials (unnormalized O bf16 + m*SC,l) merged by merge_kernel.
// ---------------------------------------------------------------------------
__global__ __launch_bounds__(256, 2) void flash_kernel(
    const uint8_t* __restrict__ qk, const uint8_t* __restrict__ vt,
    bf16* __restrict__ op0, bf16* __restrict__ op1, float* __restrict__ ml)
{
    __shared__ char smem[31232];
    uint8_t* sK  = (uint8_t*)smem;           // [32][400]  (25 chunks/row)
    uint8_t* sVT = (uint8_t*)(smem + 12800); // [384][48]  (3 chunks/row)
    const int tid = threadIdx.x;
    const int l = tid & 63, w = tid >> 6;
    const int l31 = l & 31, hi2 = l >> 5;
    const int wq = w >> 1, wd = w & 1;
    const int qt = blockIdx.x, bh = blockIdx.y;
    const int b = bh >> 1, half = bh & 1;
    const int q0 = b * 4096 + qt * 64;           // global token base of q-tile
    const int kvbase = b * 4096 + half * 2048;
    const float SC = 0.07362217057594547f;  // (1/sqrt(384)) * log2(e)

    // Q B-frags (fp8): lane holds Q[q0+wq*32+l31][ks*16+hi2*8+j], j=0..7
    long qf[24];
    {
        const uint8_t* qrow = qk + (size_t)(q0 + wq * 32 + l31) * 768;
#pragma unroll
        for (int ks = 0; ks < 24; ++ks)
            qf[ks] = *(const long*)(qrow + ks * 16 + hi2 * 8);
    }

    f32x16 o[6] = {};
    float m = -1e30f, lsum = 0.f;   // m in raw-score domain

    for (int kt = 0; kt < 64; ++kt) {
        __syncthreads();
        const int kv0 = kvbase + kt * 32;
        {   // stage K tile [32][384]fp8 (+16B pad) and V^T tile [384][32]fp8 (+16B pad)
            const uint8_t* kb = qk + (size_t)kv0 * 768 + 384;
#pragma unroll
            for (int i = 0; i < 4; ++i) {
                int ci = i * 256 + tid;
                if (ci < 800) {                        // 32 rows * 25 chunks
                    int row = ci / 25, off = ci % 25;  // off==24 -> pad slack
                    gload16(kb + (size_t)row * 768 + off * 16, sK + ci * 16);
                }
            }
            const uint8_t* vb = vt + kv0;
#pragma unroll
            for (int i = 0; i < 5; ++i) {
                int ci = i * 256 + tid;
                if (ci < 1152) {                       // 384 rows * 3 chunks
                    int row = ci / 3, off = ci % 3;    // off==2 -> pad slack
                    gload16(vb + (size_t)row * 16384 + off * 16, sVT + ci * 16);
                }
            }
        }
        __syncthreads();

        // S^T[kv][q] raw scores: A = K rows (kv), B = Q regs
        f32x16 s = {};
#pragma unroll
        for (int ks = 0; ks < 24; ++ks) {
            long ak = *(const long*)(sK + (size_t)l31 * 400 + ks * 16 + hi2 * 8);
            s = MFMA32F8(ak, qf[ks], s);
        }

        // online softmax: kv in regs (+xor32 partner), q = l31 per-lane
        float t = s[0];
#pragma unroll
        for (int r = 1; r < 16; ++r) t = fmaxf(t, s[r]);
        t = fmaxf(t, __shfl_xor(t, 32));
        if (__any(t > m)) {                    // new running max (rare after warmup)
            float mn = fmaxf(m, t);
            float alpha = exp2f((m - mn) * SC);
            m = mn;
            lsum *= alpha;
#pragma unroll
            for (int dt = 0; dt < 6; ++dt)
#pragma unroll
                for (int r = 0; r < 16; ++r) o[dt][r] *= alpha;
        }
        float p[16];
        float rs = 0.f;
        float msc = m * SC;
#pragma unroll
        for (int r = 0; r < 16; ++r) { p[r] = exp2f(fmaf(s[r], SC, -msc)); rs += p[r]; }
        rs += __shfl_xor(rs, 32);
        lsum += rs;

        // pack P to fp8 dwords; build PV B-frags in-register via xor32.
        // reg r holds kv=(r&3)+8*(r>>2)+4*hi2; dword i holds kv {8i..8i+3}+4*hi2.
        int d0 = __builtin_amdgcn_cvt_pk_fp8_f32(p[0], p[1], 0, false);
        d0     = __builtin_amdgcn_cvt_pk_fp8_f32(p[2], p[3], d0, true);
        int d1 = __builtin_amdgcn_cvt_pk_fp8_f32(p[4], p[5], 0, false);
        d1     = __builtin_amdgcn_cvt_pk_fp8_f32(p[6], p[7], d1, true);
        int d2 = __builtin_amdgcn_cvt_pk_fp8_f32(p[8], p[9], 0, false);
        d2     = __builtin_amdgcn_cvt_pk_fp8_f32(p[10], p[11], d2, true);
        int d3 = __builtin_amdgcn_cvt_pk_fp8_f32(p[12], p[13], 0, false);
        d3     = __builtin_amdgcn_cvt_pk_fp8_f32(p[14], p[15], d3, true);
        int x0 = __shfl_xor(d0, 32), x1 = __shfl_xor(d1, 32);
        int x2 = __shfl_xor(d2, 32), x3 = __shfl_xor(d3, 32);
        int pw[4];
        pw[0] = hi2 ? x1 : d0;  pw[1] = hi2 ? d1 : x0;   // frag ks=0: kv 0..15
        pw[2] = hi2 ? x3 : d2;  pw[3] = hi2 ? d3 : x2;   // frag ks=1: kv 16..31
        long pf0 = *(long*)&pw[0];
        long pf1 = *(long*)&pw[2];

        // O^T[d][q] += V^T · P^T   (A-frag: V^T rows = d, k = kv)
#pragma unroll
        for (int dt = 0; dt < 6; ++dt) {
            long av0 = *(const long*)(sVT + (size_t)(wd * 192 + dt * 32 + l31) * 48 + hi2 * 8);
            long av1 = *(const long*)(sVT + (size_t)(wd * 192 + dt * 32 + l31) * 48 + 16 + hi2 * 8);
            o[dt] = MFMA32F8(av0, pf0, o[dt]);
            o[dt] = MFMA32F8(av1, pf1, o[dt]);
        }
    }

    // epilogue: per-wave O^T -> O transpose through LDS (reuse tile space)
    __syncthreads();
    float* tr = (float*)(smem + w * 4608);       // [32 q][36 pitch] fp32
    bf16* dst = half ? op1 : op0;
#pragma unroll
    for (int dt = 0; dt < 6; ++dt) {
#pragma unroll
        for (int r = 0; r < 16; ++r) {
            int d = (r & 3) + 8 * (r >> 2) + 4 * hi2;
            tr[l31 * 36 + d] = o[dt][r];
        }
        int q = l >> 1, dh = (l & 1) * 16;
        f32x4 v0 = *(f32x4*)(tr + q * 36 + dh + 0);
        f32x4 v1 = *(f32x4*)(tr + q * 36 + dh + 4);
        f32x4 v2 = *(f32x4*)(tr + q * 36 + dh + 8);
        f32x4 v3 = *(f32x4*)(tr + q * 36 + dh + 12);
        bf16x8 h0, h1;
#pragma unroll
        for (int j = 0; j < 4; ++j) {
            h0[j] = (bf16)v0[j]; h0[4 + j] = (bf16)v1[j];
            h1[j] = (bf16)v2[j]; h1[4 + j] = (bf16)v3[j];
        }
        size_t tok = (size_t)(q0 + wq * 32 + q);
        bf16* drow = dst + tok * 384 + wd * 192 + dt * 32 + dh;
        *(bf16x8*)(drow + 0) = h0;
        *(bf16x8*)(drow + 8) = h1;
        __syncthreads();                          // keep waves in step (cheap)
    }
    if (wd == 0 && hi2 == 0) {
        int tok = q0 + wq * 32 + l31;
        ml[(size_t)(half * 16384 + tok) * 2 + 0] = m * SC;   // scaled domain
        ml[(size_t)(half * 16384 + tok) * 2 + 1] = lsum;
    }
}

// ---------------------------------------------------------------------------
// Merge the two kv-half partials: out = (a0*O0 + a1*O1) / (a0*l0 + a1*l1).
// One wave per token; p1 aliases ob (in-place safe, element-wise).
// ---------------------------------------------------------------------------
__global__ __launch_bounds__(256) void merge_kernel(
    const bf16* __restrict__ p0, const bf16* __restrict__ p1,
    const float* __restrict__ ml, bf16* __restrict__ ob)
{
    int tok = blockIdx.x * 4 + (threadIdx.x >> 6);
    int l = threadIdx.x & 63;
    float m0 = ml[(size_t)tok * 2 + 0], l0 = ml[(size_t)tok * 2 + 1];
    float m1 = ml[(size_t)(16384 + tok) * 2 + 0], l1 = ml[(size_t)(16384 + tok) * 2 + 1];
    float mM = fmaxf(m0, m1);
    float a0 = exp2f(m0 - mM), a1 = exp2f(m1 - mM);
    float inv = 1.0f / (a0 * l0 + a1 * l1);
    float w0 = a0 * inv, w1 = a1 * inv;
    if (l < 48) {
        size_t off = (size_t)tok * 384 + l * 8;
        bf16x8 v0 = *(const bf16x8*)(p0 + off);
        bf16x8 v1 = *(const bf16x8*)(p1 + off);
        bf16x8 r;
#pragma unroll
        for (int j = 0; j < 8; ++j)
            r[j] = (bf16)((float)v0[j] * w0 + (float)v1[j] * w1);
        *(bf16x8*)(ob + off) = r;
    }
}

// ---------------------------------------------------------------------------
extern "C" void kernel_launch(void* const* d_in, const int* in_sizes, int n_in,
                              void* d_out, int out_size, void* d_ws, size_t ws_size,
                              hipStream_t stream) {
    const float* x      = (const float*)d_in[0];
    const float* gamma  = (const float*)d_in[1];
    const float* w_qkv  = (const float*)d_in[2];
    const float* b_qkv  = (const float*)d_in[3];
    const float* w_proj = (const float*)d_in[4];
    const float* b_proj = (const float*)d_in[5];
    float* out = (float*)d_out;

    // workspace carve (~46 MiB); staging 16B overreads at buffer tails land
    // in the next ws buffer. xn is dead after the two gemms -> reused as op0.
    char* ws = (char*)d_ws;
    bf16* xn  = (bf16*)ws;    ws += (size_t)16384 * 384 * 2;   // normalized x / flash partial-0
    uint8_t* qkb = (uint8_t*)ws; ws += (size_t)16384 * 768;    // Q|K fp8, [tok][768]
    uint8_t* vtb = (uint8_t*)ws; ws += (size_t)384 * 16384;    // V^T fp8, [d][tok]
    bf16* ob  = (bf16*)ws;    ws += (size_t)16384 * 384 * 2;   // flash partial-1 / merged attn out
    bf16* wq  = (bf16*)ws;    ws += (size_t)1152 * 384 * 2;    // w_qkv bf16
    bf16* wp  = (bf16*)ws;    ws += (size_t)384 * 384 * 2;     // w_proj bf16
    float* mlb = (float*)ws;  ws += (size_t)2 * 16384 * 2 * 4; // m*SC,l per (half, tok)

    convert_w<<<2304, 256, 0, stream>>>(w_qkv, w_proj, wq, wp);
    norm_kernel<<<256, 64, 0, stream>>>(x, gamma, xn);
    // QK fp8: C[tok][o] = xn @ w_qk^T + b_qkv[o], o in [0,768)
    gemm_bt<<<dim3(6, 128), 256, 0, stream>>>(xn, wq, nullptr, b_qkv, nullptr, qkb, 0, 768);
    // V^T fp8: C[d][tok] = w_v @ xn^T + b_qkv[768+d]
    gemm_bt<<<dim3(128, 3), 256, 0, stream>>>(wq + (size_t)768 * 384, xn,
                                              b_qkv + 768, nullptr, nullptr, vtb, 1, 16384);
    flash_kernel<<<dim3(64, 8), 256, 0, stream>>>(qkb, vtb, xn, ob, mlb);
    merge_kernel<<<4096, 256, 0, stream>>>(xn, ob, mlb, ob);
    // proj (transposed output) + bias + residual, fp32 out
    gemm_bt<<<dim3(128, 3), 256, 0, stream>>>(wp, ob, b_proj, nullptr, x, out, 2, 0);
}